// Round 8
// baseline (197.025 us; speedup 1.0000x reference)
//
#include <hip/hip_runtime.h>

typedef __bf16 bf16;
typedef bf16 bf16x4 __attribute__((ext_vector_type(4)));
typedef bf16 bf16x8 __attribute__((ext_vector_type(8)));
typedef float floatx4 __attribute__((ext_vector_type(4)));

#define NB 8
#define NQ 1024
#define NK 1024
#define DIM 512
#define NH 8
#define DH 64

// async global->LDS, 16B per lane. LDS dest must be wave-uniform base + lane*16B.
__device__ __forceinline__ void async16(const void* g, void* l) {
    __builtin_amdgcn_global_load_lds(
        (const __attribute__((address_space(1))) unsigned int*)(unsigned long long)(g),
        (__attribute__((address_space(3))) unsigned int*)(unsigned long long)(l),
        16, 0, 0);
}

// ---------------------------------------------------------------------------
// prep_fused: blocks [0,4096): cast Q,K fp32->bf16 (float4 vectorized);
//             blocks [4096,4352): Wt[w][n][k] = (bf16)W[k][n], LDS 64x64 tiles.
// ---------------------------------------------------------------------------
__global__ __launch_bounds__(256) void prep_fused(
    const float* __restrict__ Q, const float* __restrict__ K,
    const float* __restrict__ Wq, const float* __restrict__ Wk,
    const float* __restrict__ Wv, const float* __restrict__ Wo,
    bf16* __restrict__ Qb, bf16* __restrict__ Kb, bf16* __restrict__ Wt)
{
    __shared__ bf16 Tl[64][68];
    const int bid = blockIdx.x;
    if (bid < 4096) {
        const int i = bid * 256 + threadIdx.x;   // float4 index
        float4 a = ((const float4*)Q)[i];
        float4 c = ((const float4*)K)[i];
        bf16x4 qa = {(bf16)a.x, (bf16)a.y, (bf16)a.z, (bf16)a.w};
        bf16x4 ka = {(bf16)c.x, (bf16)c.y, (bf16)c.z, (bf16)c.w};
        *(bf16x4*)(Qb + (size_t)i * 4) = qa;
        *(bf16x4*)(Kb + (size_t)i * 4) = ka;
    } else {
        const int bid2 = bid - 4096;
        const int w = bid2 >> 6;
        const int bx = bid2 & 7, by = (bid2 >> 3) & 7;
        const float* W = (w == 0) ? Wq : (w == 1) ? Wk : (w == 2) ? Wv : Wo;
        bf16* out = Wt + (size_t)w * DIM * DIM;
        const int k0 = bx * 64, n0 = by * 64;
        const int tx = threadIdx.x & 15, ty = threadIdx.x >> 4;
        for (int pass = 0; pass < 4; ++pass) {
            int k = ty + pass * 16;
            float4 v = *(const float4*)&W[(size_t)(k0 + k) * DIM + n0 + tx * 4];
            Tl[tx * 4 + 0][k] = (bf16)v.x;
            Tl[tx * 4 + 1][k] = (bf16)v.y;
            Tl[tx * 4 + 2][k] = (bf16)v.z;
            Tl[tx * 4 + 3][k] = (bf16)v.w;
        }
        __syncthreads();
        for (int pass = 0; pass < 4; ++pass) {
            int n = ty + pass * 16;
            bf16x4 ov = *(const bf16x4*)&Tl[n][tx * 4];
            *(bf16x4*)&out[(size_t)(n0 + n) * DIM + k0 + tx * 4] = ov;
        }
    }
}

// ---------------------------------------------------------------------------
// proj_fused: 128x128 tiles, BK=64, XOR-swizzled async staging, m-minor
// block mapping (XCD L2 locality).
// blocks [0,256):   Q proj -> Qp head layout [b,h,q,64]
// blocks [256,768): KV proj: n<512 -> Kp head layout; n>=512 -> Vpt
//                   [b,h,d,1024] via in-LDS transpose (coalesced stores).
// ---------------------------------------------------------------------------
__global__ __launch_bounds__(256) void proj_fused(
    const bf16* __restrict__ Qb, const bf16* __restrict__ Kb,
    const bf16* __restrict__ Wt,
    const float* __restrict__ bq, const float* __restrict__ bk,
    const float* __restrict__ bv,
    bf16* __restrict__ Qp, bf16* __restrict__ Kp, bf16* __restrict__ Vpt)
{
    __shared__ __attribute__((aligned(16))) bf16 sh[16384];  // As|Bs, reused as Tb
    bf16* As = sh;            // 128 x 64
    bf16* Bs = sh + 8192;     // 128 x 64
    const int t = threadIdx.x;
    const int wave = t >> 6, lane = t & 63, quad = lane >> 4, l16 = lane & 15;
    const int wr = wave >> 1, wc = wave & 1;
    const int bid = blockIdx.x;
    const bool isQ = bid < 256;
    const bf16* A; const bf16* W; int m0, n0;
    if (isQ) { A = Qb; W = Wt;             m0 = (bid & 63) * 128;  n0 = (bid >> 6) * 128; }
    else     { int b2 = bid - 256;
               A = Kb; W = Wt + 512 * DIM; m0 = (b2 & 63) * 128;   n0 = (b2 >> 6) * 128; }

    const int r1 = t >> 3, s1 = t & 7;
    const int p1 = s1 ^ (r1 & 7);          // rows r1+32j keep row&7
    const bf16* aSrc = A + (size_t)(m0 + r1) * DIM + p1 * 8;
    const bf16* wSrc = W + (size_t)(n0 + r1) * DIM + p1 * 8;

    floatx4 acc[4][4];
    for (int i = 0; i < 4; ++i)
        for (int j = 0; j < 4; ++j) acc[i][j] = (floatx4){0.f, 0.f, 0.f, 0.f};

    for (int kt = 0; kt < 8; ++kt) {
        __syncthreads();
        const int ko = kt * 64;
        #pragma unroll
        for (int j = 0; j < 4; ++j) {
            async16(aSrc + ko + (size_t)j * 32 * DIM, As + (t + j * 256) * 8);
            async16(wSrc + ko + (size_t)j * 32 * DIM, Bs + (t + j * 256) * 8);
        }
        __syncthreads();
        #pragma unroll
        for (int ks = 0; ks < 2; ++ks) {
            bf16x8 af[4], bfr[4];
            #pragma unroll
            for (int mi = 0; mi < 4; ++mi) {
                const int row = wr * 64 + mi * 16 + l16;
                af[mi] = *(const bf16x8*)(As + row * 64 + (((ks * 4 + quad) ^ (row & 7)) << 3));
            }
            #pragma unroll
            for (int ni = 0; ni < 4; ++ni) {
                const int row = wc * 64 + ni * 16 + l16;
                bfr[ni] = *(const bf16x8*)(Bs + row * 64 + (((ks * 4 + quad) ^ (row & 7)) << 3));
            }
            #pragma unroll
            for (int mi = 0; mi < 4; ++mi)
                #pragma unroll
                for (int ni = 0; ni < 4; ++ni)
                    acc[mi][ni] = __builtin_amdgcn_mfma_f32_16x16x32_bf16(
                        af[mi], bfr[ni], acc[mi][ni], 0, 0, 0);
        }
    }

    const bool isV = (!isQ) && (n0 >= 512);
    if (!isV) {
        bf16* out = isQ ? Qp : Kp;
        const float* bias = isQ ? bq : bk;
        for (int ni = 0; ni < 4; ++ni) {
            const int n = n0 + wc * 64 + ni * 16 + l16;
            const float bb = bias[n];
            const int hd = n >> 6, d = n & 63;
            for (int mi = 0; mi < 4; ++mi) {
                for (int r = 0; r < 4; ++r) {
                    const int m = m0 + wr * 64 + mi * 16 + quad * 4 + r;
                    const int b = m >> 10, q = m & 1023;
                    out[((size_t)(b * 8 + hd) * 1024 + q) * 64 + d] = (bf16)(acc[mi][ni][r] + bb);
                }
            }
        }
    } else {
        __syncthreads();
        for (int ni = 0; ni < 4; ++ni) {
            const int n = wc * 64 + ni * 16 + l16;           // local n
            const float bb = bv[n0 + n - 512];
            for (int mi = 0; mi < 4; ++mi) {
                const int mb = wr * 64 + mi * 16 + quad * 4;  // local m base (r=0..3)
                const int slot = ((mb >> 3) ^ (n & 15));
                bf16x4 pk = {(bf16)(acc[mi][ni][0] + bb), (bf16)(acc[mi][ni][1] + bb),
                             (bf16)(acc[mi][ni][2] + bb), (bf16)(acc[mi][ni][3] + bb)};
                *(bf16x4*)(sh + n * 128 + slot * 8 + (mb & 7)) = pk;
            }
        }
        __syncthreads();
        const int n = t >> 1, hf = t & 1;
        const int nv = n0 + n - 512, hd = nv >> 6, d = nv & 63;
        const int b = m0 >> 10, qb = m0 & 1023;
        bf16* dst = Vpt + ((size_t)(b * 8 + hd) * 64 + d) * 1024 + qb + hf * 64;
        #pragma unroll
        for (int j = 0; j < 8; ++j) {
            const int ch = hf * 8 + j;
            const int slot = ch ^ (n & 15);
            bf16x8 v8 = *(const bf16x8*)(sh + n * 128 + slot * 8);
            *(bf16x8*)(dst + j * 8) = v8;
        }
    }
}

// ---------------------------------------------------------------------------
// attn: flash attention per (b,h). 128-THREAD blocks (2 waves x 32 q = 64 q),
// grid 1024 -> 24KB LDS -> 6 blocks/CU = 12 waves/CU (VALU/MFMA overlap).
// q=32/wave (two 16-row groups sharing K/V frags) keeps VALU:MFMA ~2:1.
// __expf (fast v_exp_f32 — exp2f regressed to libm in R7!). S^T trick
// (A=K, B=Q) -> packed b64 P writes. XOR-swizzled conflict-free LDS.
// ---------------------------------------------------------------------------
__global__ __launch_bounds__(128) void attn_kernel(
    const bf16* __restrict__ Qp, const bf16* __restrict__ Kp,
    const bf16* __restrict__ Vpt, const int* __restrict__ mask,
    bf16* __restrict__ Oa)
{
    const int bh = blockIdx.x & 63, qblk = blockIdx.x >> 6;  // qblk 0..15
    const int b = bh >> 3, hd = bh & 7;
    const int t = threadIdx.x;
    const int wave = t >> 6, lane = t & 63, quad = lane >> 4, l16 = lane & 15;
    const float scale = 1.25f;   // 1/(sqrt(64)*0.1)

    __shared__ __attribute__((aligned(16))) bf16 Kt[64 * 64];
    __shared__ __attribute__((aligned(16))) bf16 Vt[64 * 64];
    __shared__ __attribute__((aligned(16))) bf16 Pl[2][32 * 64];

    const bf16* Qbase = Qp + ((size_t)bh * NQ + qblk * 64 + wave * 32) * DH;
    const bf16* Kbase = Kp + (size_t)bh * NK * DH;
    const bf16* Vbase = Vpt + (size_t)bh * DH * NK;
    const int* mrow = mask + b * NK;

    bf16x8 qf[2][2];
    for (int g = 0; g < 2; ++g)
        for (int hh = 0; hh < 2; ++hh)
            qf[g][hh] = *(const bf16x8*)(Qbase + (g * 16 + l16) * DH + hh * 32 + quad * 8);

    floatx4 o[2][4];
    float lsum[2];
    for (int g = 0; g < 2; ++g) {
        lsum[g] = 0.f;
        for (int i = 0; i < 4; ++i) o[g][i] = (floatx4){0.f, 0.f, 0.f, 0.f};
    }

    // staging: 512 chunks per tile, 128 threads -> 4 chunks each (rows r1+16j)
    const int r1 = t >> 3, s1 = t & 7;
    const int p1 = s1 ^ (r1 & 7);          // (r1+16j)&7 == r1&7
    const bf16* kSrc = Kbase + r1 * 64 + p1 * 8;            // + kt*4096
    const bf16* vSrc = Vbase + (size_t)r1 * 1024 + p1 * 8;  // + kt*64

    for (int kt = 0; kt < NK / 64; ++kt) {
        __syncthreads();
        #pragma unroll
        for (int j = 0; j < 4; ++j) {
            async16(kSrc + kt * 4096 + j * 16 * 64, Kt + (t + j * 128) * 8);
            async16(vSrc + kt * 64 + (size_t)j * 16 * 1024, Vt + (t + j * 128) * 8);
        }
        __syncthreads();

        // K A-frags (lane = key-within-subtile), shared by both q-groups
        bf16x8 kb[4][2];
        #pragma unroll
        for (int sub = 0; sub < 4; ++sub) {
            const int rowk = sub * 16 + l16;
            kb[sub][0] = *(const bf16x8*)(Kt + rowk * 64 + ((quad ^ (rowk & 7)) << 3));
            kb[sub][1] = *(const bf16x8*)(Kt + rowk * 64 + (((quad + 4) ^ (rowk & 7)) << 3));
        }
        // S^T = K Q^T: C col = q (l16), row = key-within-sub (quad*4+r)
        floatx4 sf[2][4];
        #pragma unroll
        for (int g = 0; g < 2; ++g)
            #pragma unroll
            for (int sub = 0; sub < 4; ++sub) {
                floatx4 s = {0.f, 0.f, 0.f, 0.f};
                s = __builtin_amdgcn_mfma_f32_16x16x32_bf16(kb[sub][0], qf[g][0], s, 0, 0, 0);
                s = __builtin_amdgcn_mfma_f32_16x16x32_bf16(kb[sub][1], qf[g][1], s, 0, 0, 0);
                sf[g][sub] = s;
            }
        // exp + mask (int4 per sub: keys kt*64+sub*16+quad*4+r) + row sums
        #pragma unroll
        for (int sub = 0; sub < 4; ++sub) {
            const int4 m4 = *(const int4*)&mrow[kt * 64 + sub * 16 + quad * 4];
            const float md0 = m4.x ? 0.f : -3.0e38f;
            const float md1 = m4.y ? 0.f : -3.0e38f;
            const float md2 = m4.z ? 0.f : -3.0e38f;
            const float md3 = m4.w ? 0.f : -3.0e38f;
            #pragma unroll
            for (int g = 0; g < 2; ++g) {
                float p0 = __expf(sf[g][sub][0] * scale + md0);
                float p1v = __expf(sf[g][sub][1] * scale + md1);
                float p2 = __expf(sf[g][sub][2] * scale + md2);
                float p3 = __expf(sf[g][sub][3] * scale + md3);
                sf[g][sub][0] = p0; sf[g][sub][1] = p1v;
                sf[g][sub][2] = p2; sf[g][sub][3] = p3;
                lsum[g] += p0 + p1v + p2 + p3;
            }
        }
        // P -> Pl[q][key]: packed b64 writes, XOR part-swizzle
        #pragma unroll
        for (int g = 0; g < 2; ++g)
            #pragma unroll
            for (int sub = 0; sub < 4; ++sub) {
                bf16x4 pk = {(bf16)sf[g][sub][0], (bf16)sf[g][sub][1],
                             (bf16)sf[g][sub][2], (bf16)sf[g][sub][3]};
                const int slot = (sub * 2 + (quad >> 1)) ^ (l16 & 7);
                *(bf16x4*)&Pl[wave][(g * 16 + l16) * 64 + slot * 8 + (quad & 1) * 4] = pk;
            }
        bf16x8 af[2][2];
        #pragma unroll
        for (int g = 0; g < 2; ++g)
            #pragma unroll
            for (int hh = 0; hh < 2; ++hh) {
                const int slot = (hh * 4 + quad) ^ (l16 & 7);
                af[g][hh] = *(const bf16x8*)&Pl[wave][(g * 16 + l16) * 64 + slot * 8];
            }
        // O += P V (A = P rows, B = V^T rows), V frags shared by both groups
        #pragma unroll
        for (int dsub = 0; dsub < 4; ++dsub) {
            const int rowd = dsub * 16 + l16;
            bf16x8 v0 = *(const bf16x8*)(Vt + rowd * 64 + ((quad ^ (rowd & 7)) << 3));
            bf16x8 v1 = *(const bf16x8*)(Vt + rowd * 64 + (((quad + 4) ^ (rowd & 7)) << 3));
            #pragma unroll
            for (int g = 0; g < 2; ++g) {
                o[g][dsub] = __builtin_amdgcn_mfma_f32_16x16x32_bf16(af[g][0], v0, o[g][dsub], 0, 0, 0);
                o[g][dsub] = __builtin_amdgcn_mfma_f32_16x16x32_bf16(af[g][1], v1, o[g][dsub], 0, 0, 0);
            }
        }
    }

    // reduce row sums (lane l16 = q) across quad groups; broadcast; store
    for (int g = 0; g < 2; ++g) {
        float lr = lsum[g];
        lr += __shfl_xor(lr, 16, 64);
        lr += __shfl_xor(lr, 32, 64);
        const float inv = 1.f / lr;
        float linv[4];
        for (int r = 0; r < 4; ++r) linv[r] = __shfl(inv, quad * 4 + r, 64);
        for (int dsub = 0; dsub < 4; ++dsub) {
            for (int r = 0; r < 4; ++r) {
                const int q = qblk * 64 + wave * 32 + g * 16 + quad * 4 + r;
                const int col = hd * 64 + dsub * 16 + l16;
                Oa[((size_t)(b * NQ + q)) * DIM + col] = (bf16)(o[g][dsub][r] * linv[r]);
            }
        }
    }
}

// ---------------------------------------------------------------------------
// ffn_ln: fused  Y = Oa + relu(Oa @ Wo^T + bo)  then  LayerNorm(Y)*gamma+beta.
// Block = 16 rows x FULL 512 cols; 512 blocks (2/CU -> drains overlap).
// A staged ONCE (also residual source); B per BK=32 k-tile; stats alias Bs.
// ---------------------------------------------------------------------------
__global__ __launch_bounds__(256) void ffn_ln(
    const bf16* __restrict__ Oa, const bf16* __restrict__ W,
    const float* __restrict__ bo, const float* __restrict__ gamma,
    const float* __restrict__ beta, float* __restrict__ out)
{
    __shared__ __attribute__((aligned(16))) bf16 As[16 * 512];   // 16 KB
    __shared__ __attribute__((aligned(16))) bf16 Bs[512 * 32];   // 32 KB
    const int t = threadIdx.x;
    const int wave = t >> 6, lane = t & 63, quad = lane >> 4, l16 = lane & 15;
    const int m0 = blockIdx.x * 16;

    // stage 16 A rows once: 1024 chunks / 256 thr = 4 each
    #pragma unroll
    for (int j = 0; j < 4; ++j) {
        const int c = t + j * 256;
        const int row = c >> 6, slot = c & 63;
        const int p = (slot & 56) | ((slot & 7) ^ (row & 7));
        async16(Oa + (size_t)(m0 + row) * DIM + p * 8, As + row * 512 + slot * 8);
    }

    floatx4 acc[8];
    for (int j = 0; j < 8; ++j) acc[j] = (floatx4){0.f, 0.f, 0.f, 0.f};

    for (int kt = 0; kt < 16; ++kt) {
        __syncthreads();
        // stage B k-tile: 2048 chunks: n = c>>2, slot = c&3, part = slot^((n>>1)&3)
        #pragma unroll
        for (int j = 0; j < 8; ++j) {
            const int c = t + j * 256;
            const int n = c >> 2, slot = c & 3;
            const int p = slot ^ ((n >> 1) & 3);
            async16(W + (size_t)n * DIM + kt * 32 + p * 8, Bs + n * 32 + slot * 8);
        }
        __syncthreads();
        bf16x8 af, bfr[8];
        {
            const int part = kt * 4 + quad;
            const int slot = (part & 56) | ((part & 7) ^ (l16 & 7));
            af = *(const bf16x8*)(As + l16 * 512 + slot * 8);
        }
        #pragma unroll
        for (int ni = 0; ni < 8; ++ni) {
            const int n = wave * 128 + ni * 16 + l16;
            const int slot = quad ^ ((n >> 1) & 3);
            bfr[ni] = *(const bf16x8*)(Bs + n * 32 + slot * 8);
        }
        #pragma unroll
        for (int ni = 0; ni < 8; ++ni)
            acc[ni] = __builtin_amdgcn_mfma_f32_16x16x32_bf16(af, bfr[ni], acc[ni], 0, 0, 0);
    }

    // epilogue: y = res + relu(acc + bo)
    #pragma unroll
    for (int ni = 0; ni < 8; ++ni) {
        const int n = wave * 128 + ni * 16 + l16;
        const float bb = bo[n];
        const int part = n >> 3, noff = n & 7;
        #pragma unroll
        for (int r = 0; r < 4; ++r) {
            const int row = quad * 4 + r;
            const int slot = (part & 56) | ((part & 7) ^ (row & 7));
            const float res = (float)As[row * 512 + slot * 8 + noff];
            acc[ni][r] = res + fmaxf(acc[ni][r] + bb, 0.f);
        }
    }

    // LN stats (alias Bs, dead now)
    __syncthreads();
    float* Sm  = (float*)Bs;        // [4][16]
    float* Sq  = Sm + 64;           // [4][16]
    float* Mu  = Sm + 128;          // [16]
    float* Inv = Sm + 144;          // [16]
    #pragma unroll
    for (int r = 0; r < 4; ++r) {
        float s = 0.f, q2 = 0.f;
        #pragma unroll
        for (int ni = 0; ni < 8; ++ni) {
            const float v = acc[ni][r];
            s += v; q2 += v * v;
        }
        s  += __shfl_xor(s, 1, 64);  q2 += __shfl_xor(q2, 1, 64);
        s  += __shfl_xor(s, 2, 64);  q2 += __shfl_xor(q2, 2, 64);
        s  += __shfl_xor(s, 4, 64);  q2 += __shfl_xor(q2, 4, 64);
        s  += __shfl_xor(s, 8, 64);  q2 += __shfl_xor(q2, 8, 64);
        if (l16 == 0) {
            const int row = quad * 4 + r;
            Sm[wave * 16 + row] = s;
            Sq[wave * 16 + row] = q2;
        }
    }
    __syncthreads();
    if (t < 16) {
        const float s  = Sm[t] + Sm[16 + t] + Sm[32 + t] + Sm[48 + t];
        const float q2 = Sq[t] + Sq[16 + t] + Sq[32 + t] + Sq[48 + t];
        const float mu = s * (1.f / 512.f);
        const float var = q2 * (1.f / 512.f) - mu * mu;
        Mu[t] = mu;
        Inv[t] = rsqrtf(var + 1e-5f);
    }
    __syncthreads();

    #pragma unroll
    for (int ni = 0; ni < 8; ++ni) {
        const int n = wave * 128 + ni * 16 + l16;
        const float gv = gamma[n], btv = beta[n];
        #pragma unroll
        for (int r = 0; r < 4; ++r) {
            const int row = quad * 4 + r;
            out[(size_t)(m0 + row) * DIM + n] =
                (acc[ni][r] - Mu[row]) * Inv[row] * gv + btv;
        }
    }
}

// ---------------------------------------------------------------------------
extern "C" void kernel_launch(void* const* d_in, const int* in_sizes, int n_in,
                              void* d_out, int out_size, void* d_ws, size_t ws_size,
                              hipStream_t stream) {
    const float* Q  = (const float*)d_in[0];
    const float* K  = (const float*)d_in[1];
    const int*   mask = (const int*)d_in[2];
    const float* Wq = (const float*)d_in[3];
    const float* bq = (const float*)d_in[4];
    const float* Wk = (const float*)d_in[5];
    const float* bk = (const float*)d_in[6];
    const float* Wv = (const float*)d_in[7];
    const float* bv = (const float*)d_in[8];
    const float* Wo = (const float*)d_in[9];
    const float* bo = (const float*)d_in[10];
    const float* gamma = (const float*)d_in[11];
    const float* beta  = (const float*)d_in[12];

    char* ws = (char*)d_ws;
    bf16* Wt  = (bf16*)(ws);                   // 2 MB (4 x 512x512 bf16, transposed)
    bf16* Qb  = (bf16*)(ws + 2097152);         // 8 MB
    bf16* Kb  = (bf16*)(ws + 10485760);        // 8 MB
    bf16* Qp  = (bf16*)(ws + 18874368);        // 8 MB  [b,h,q,64]
    bf16* Kp  = (bf16*)(ws + 27262976);        // 8 MB  [b,h,k,64]
    bf16* Vpt = (bf16*)(ws + 35651584);        // 8 MB  [b,h,d,1024]
    bf16* Oa  = (bf16*)(ws + 44040192);        // 8 MB  [b,q,512]
    float* out = (float*)d_out;

    prep_fused<<<4352, 256, 0, stream>>>(Q, K, Wq, Wk, Wv, Wo, Qb, Kb, Wt);
    proj_fused<<<768, 256, 0, stream>>>(Qb, Kb, Wt, bq, bk, bv, Qp, Kp, Vpt);
    attn_kernel<<<1024, 128, 0, stream>>>(Qp, Kp, Vpt, mask, Oa);
    ffn_ln<<<512, 256, 0, stream>>>(Oa, Wt + 3 * 262144, bo, gamma, beta, out);
}

// Round 9
// 178.198 us; speedup vs baseline: 1.1057x; 1.1057x over previous
//
#include <hip/hip_runtime.h>

typedef __bf16 bf16;
typedef bf16 bf16x4 __attribute__((ext_vector_type(4)));
typedef bf16 bf16x8 __attribute__((ext_vector_type(8)));
typedef float floatx4 __attribute__((ext_vector_type(4)));

#define NB 8
#define NQ 1024
#define NK 1024
#define DIM 512
#define NH 8
#define DH 64

// async global->LDS, 16B per lane. LDS dest must be wave-uniform base + lane*16B.
__device__ __forceinline__ void async16(const void* g, void* l) {
    __builtin_amdgcn_global_load_lds(
        (const __attribute__((address_space(1))) unsigned int*)(unsigned long long)(g),
        (__attribute__((address_space(3))) unsigned int*)(unsigned long long)(l),
        16, 0, 0);
}

// ---------------------------------------------------------------------------
// prep_fused: blocks [0,4096): cast Q,K fp32->bf16 (float4 vectorized);
//             blocks [4096,4352): Wt[w][n][k] = (bf16)W[k][n], LDS 64x64 tiles.
// ---------------------------------------------------------------------------
__global__ __launch_bounds__(256) void prep_fused(
    const float* __restrict__ Q, const float* __restrict__ K,
    const float* __restrict__ Wq, const float* __restrict__ Wk,
    const float* __restrict__ Wv, const float* __restrict__ Wo,
    bf16* __restrict__ Qb, bf16* __restrict__ Kb, bf16* __restrict__ Wt)
{
    __shared__ bf16 Tl[64][68];
    const int bid = blockIdx.x;
    if (bid < 4096) {
        const int i = bid * 256 + threadIdx.x;   // float4 index
        float4 a = ((const float4*)Q)[i];
        float4 c = ((const float4*)K)[i];
        bf16x4 qa = {(bf16)a.x, (bf16)a.y, (bf16)a.z, (bf16)a.w};
        bf16x4 ka = {(bf16)c.x, (bf16)c.y, (bf16)c.z, (bf16)c.w};
        *(bf16x4*)(Qb + (size_t)i * 4) = qa;
        *(bf16x4*)(Kb + (size_t)i * 4) = ka;
    } else {
        const int bid2 = bid - 4096;
        const int w = bid2 >> 6;
        const int bx = bid2 & 7, by = (bid2 >> 3) & 7;
        const float* W = (w == 0) ? Wq : (w == 1) ? Wk : (w == 2) ? Wv : Wo;
        bf16* out = Wt + (size_t)w * DIM * DIM;
        const int k0 = bx * 64, n0 = by * 64;
        const int tx = threadIdx.x & 15, ty = threadIdx.x >> 4;
        for (int pass = 0; pass < 4; ++pass) {
            int k = ty + pass * 16;
            float4 v = *(const float4*)&W[(size_t)(k0 + k) * DIM + n0 + tx * 4];
            Tl[tx * 4 + 0][k] = (bf16)v.x;
            Tl[tx * 4 + 1][k] = (bf16)v.y;
            Tl[tx * 4 + 2][k] = (bf16)v.z;
            Tl[tx * 4 + 3][k] = (bf16)v.w;
        }
        __syncthreads();
        for (int pass = 0; pass < 4; ++pass) {
            int n = ty + pass * 16;
            bf16x4 ov = *(const bf16x4*)&Tl[n][tx * 4];
            *(bf16x4*)&out[(size_t)(n0 + n) * DIM + k0 + tx * 4] = ov;
        }
    }
}

// ---------------------------------------------------------------------------
// proj_fused: 128x128 tiles, BK=64, XOR-swizzled async staging, m-minor
// block mapping (XCD L2 locality).
// blocks [0,256):   Q proj -> Qp head layout [b,h,q,64]
// blocks [256,768): KV proj: n<512 -> Kp head layout; n>=512 -> Vpt
//                   [b,h,d,1024] via in-LDS transpose (coalesced stores).
// ---------------------------------------------------------------------------
__global__ __launch_bounds__(256) void proj_fused(
    const bf16* __restrict__ Qb, const bf16* __restrict__ Kb,
    const bf16* __restrict__ Wt,
    const float* __restrict__ bq, const float* __restrict__ bk,
    const float* __restrict__ bv,
    bf16* __restrict__ Qp, bf16* __restrict__ Kp, bf16* __restrict__ Vpt)
{
    __shared__ __attribute__((aligned(16))) bf16 sh[16384];  // As|Bs, reused as Tb
    bf16* As = sh;            // 128 x 64
    bf16* Bs = sh + 8192;     // 128 x 64
    const int t = threadIdx.x;
    const int wave = t >> 6, lane = t & 63, quad = lane >> 4, l16 = lane & 15;
    const int wr = wave >> 1, wc = wave & 1;
    const int bid = blockIdx.x;
    const bool isQ = bid < 256;
    const bf16* A; const bf16* W; int m0, n0;
    if (isQ) { A = Qb; W = Wt;             m0 = (bid & 63) * 128;  n0 = (bid >> 6) * 128; }
    else     { int b2 = bid - 256;
               A = Kb; W = Wt + 512 * DIM; m0 = (b2 & 63) * 128;   n0 = (b2 >> 6) * 128; }

    const int r1 = t >> 3, s1 = t & 7;
    const int p1 = s1 ^ (r1 & 7);          // rows r1+32j keep row&7
    const bf16* aSrc = A + (size_t)(m0 + r1) * DIM + p1 * 8;
    const bf16* wSrc = W + (size_t)(n0 + r1) * DIM + p1 * 8;

    floatx4 acc[4][4];
    for (int i = 0; i < 4; ++i)
        for (int j = 0; j < 4; ++j) acc[i][j] = (floatx4){0.f, 0.f, 0.f, 0.f};

    for (int kt = 0; kt < 8; ++kt) {
        __syncthreads();
        const int ko = kt * 64;
        #pragma unroll
        for (int j = 0; j < 4; ++j) {
            async16(aSrc + ko + (size_t)j * 32 * DIM, As + (t + j * 256) * 8);
            async16(wSrc + ko + (size_t)j * 32 * DIM, Bs + (t + j * 256) * 8);
        }
        __syncthreads();
        #pragma unroll
        for (int ks = 0; ks < 2; ++ks) {
            bf16x8 af[4], bfr[4];
            #pragma unroll
            for (int mi = 0; mi < 4; ++mi) {
                const int row = wr * 64 + mi * 16 + l16;
                af[mi] = *(const bf16x8*)(As + row * 64 + (((ks * 4 + quad) ^ (row & 7)) << 3));
            }
            #pragma unroll
            for (int ni = 0; ni < 4; ++ni) {
                const int row = wc * 64 + ni * 16 + l16;
                bfr[ni] = *(const bf16x8*)(Bs + row * 64 + (((ks * 4 + quad) ^ (row & 7)) << 3));
            }
            #pragma unroll
            for (int mi = 0; mi < 4; ++mi)
                #pragma unroll
                for (int ni = 0; ni < 4; ++ni)
                    acc[mi][ni] = __builtin_amdgcn_mfma_f32_16x16x32_bf16(
                        af[mi], bfr[ni], acc[mi][ni], 0, 0, 0);
        }
    }

    const bool isV = (!isQ) && (n0 >= 512);
    if (!isV) {
        bf16* out = isQ ? Qp : Kp;
        const float* bias = isQ ? bq : bk;
        for (int ni = 0; ni < 4; ++ni) {
            const int n = n0 + wc * 64 + ni * 16 + l16;
            const float bb = bias[n];
            const int hd = n >> 6, d = n & 63;
            for (int mi = 0; mi < 4; ++mi) {
                for (int r = 0; r < 4; ++r) {
                    const int m = m0 + wr * 64 + mi * 16 + quad * 4 + r;
                    const int b = m >> 10, q = m & 1023;
                    out[((size_t)(b * 8 + hd) * 1024 + q) * 64 + d] = (bf16)(acc[mi][ni][r] + bb);
                }
            }
        }
    } else {
        __syncthreads();
        for (int ni = 0; ni < 4; ++ni) {
            const int n = wc * 64 + ni * 16 + l16;           // local n
            const float bb = bv[n0 + n - 512];
            for (int mi = 0; mi < 4; ++mi) {
                const int mb = wr * 64 + mi * 16 + quad * 4;  // local m base (r=0..3)
                const int slot = ((mb >> 3) ^ (n & 15));
                bf16x4 pk = {(bf16)(acc[mi][ni][0] + bb), (bf16)(acc[mi][ni][1] + bb),
                             (bf16)(acc[mi][ni][2] + bb), (bf16)(acc[mi][ni][3] + bb)};
                *(bf16x4*)(sh + n * 128 + slot * 8 + (mb & 7)) = pk;
            }
        }
        __syncthreads();
        const int n = t >> 1, hf = t & 1;
        const int nv = n0 + n - 512, hd = nv >> 6, d = nv & 63;
        const int b = m0 >> 10, qb = m0 & 1023;
        bf16* dst = Vpt + ((size_t)(b * 8 + hd) * 64 + d) * 1024 + qb + hf * 64;
        #pragma unroll
        for (int j = 0; j < 8; ++j) {
            const int ch = hf * 8 + j;
            const int slot = ch ^ (n & 15);
            bf16x8 v8 = *(const bf16x8*)(sh + n * 128 + slot * 8);
            *(bf16x8*)(dst + j * 8) = v8;
        }
    }
}

// ---------------------------------------------------------------------------
// attn: flash attention per (b,h). R6-best shape: 512 blocks x 4 waves,
// 128 q/block, 32 q/wave (two 16-row groups sharing K/V frags). __expf.
// S^T trick (A=K, B=Q) -> packed b64 P writes, XOR swizzles throughout.
// NEW: K/V LDS DOUBLE-BUFFER — prefetch tile kt+1 right after the barrier,
// compute tile kt; the long exp/MFMA phase hides the ~600-900cyc L2/LLC
// latency that the single-buffer barrier-drain exposed 16x per block.
// ---------------------------------------------------------------------------
__global__ __launch_bounds__(256) void attn_kernel(
    const bf16* __restrict__ Qp, const bf16* __restrict__ Kp,
    const bf16* __restrict__ Vpt, const int* __restrict__ mask,
    bf16* __restrict__ Oa)
{
    const int bh = blockIdx.x & 63, qblk = blockIdx.x >> 6;  // qblk 0..7
    const int b = bh >> 3, hd = bh & 7;
    const int t = threadIdx.x;
    const int wave = t >> 6, lane = t & 63, quad = lane >> 4, l16 = lane & 15;
    const float scale = 1.25f;   // 1/(sqrt(64)*0.1)

    __shared__ __attribute__((aligned(16))) bf16 Kt[2][64 * 64];
    __shared__ __attribute__((aligned(16))) bf16 Vt[2][64 * 64];
    __shared__ __attribute__((aligned(16))) bf16 Pl[4][32 * 64];

    const bf16* Qbase = Qp + ((size_t)bh * NQ + qblk * 128 + wave * 32) * DH;
    const bf16* Kbase = Kp + (size_t)bh * NK * DH;
    const bf16* Vbase = Vpt + (size_t)bh * DH * NK;
    const int* mrow = mask + b * NK;

    bf16x8 qf[2][2];
    for (int g = 0; g < 2; ++g)
        for (int hh = 0; hh < 2; ++hh)
            qf[g][hh] = *(const bf16x8*)(Qbase + (g * 16 + l16) * DH + hh * 32 + quad * 8);

    floatx4 o[2][4];
    float lsum[2];
    for (int g = 0; g < 2; ++g) {
        lsum[g] = 0.f;
        for (int i = 0; i < 4; ++i) o[g][i] = (floatx4){0.f, 0.f, 0.f, 0.f};
    }

    // staging: 4 async16/thread per tile (K 8KB + V 8KB)
    const int r1 = t >> 3, s1 = t & 7;
    const int p1 = s1 ^ (r1 & 7);          // (r1+32)&7 == r1&7
    const bf16* kSrc = Kbase + r1 * 64 + p1 * 8;            // + kt*4096
    const bf16* vSrc = Vbase + (size_t)r1 * 1024 + p1 * 8;  // + kt*64

    // prologue: issue tile 0 into buf 0
    async16(kSrc, Kt[0] + t * 8);
    async16(kSrc + 32 * 64, Kt[0] + (t + 256) * 8);
    async16(vSrc, Vt[0] + t * 8);
    async16(vSrc + (size_t)32 * 1024, Vt[0] + (t + 256) * 8);

    for (int kt = 0; kt < NK / 64; ++kt) {
        __syncthreads();   // tile kt loads complete; all waves done with buf (kt+1)&1
        const int cur = kt & 1;
        if (kt < NK / 64 - 1) {
            const int nxt = 1 - cur;
            async16(kSrc + (kt + 1) * 4096, Kt[nxt] + t * 8);
            async16(kSrc + (kt + 1) * 4096 + 32 * 64, Kt[nxt] + (t + 256) * 8);
            async16(vSrc + (kt + 1) * 64, Vt[nxt] + t * 8);
            async16(vSrc + (kt + 1) * 64 + (size_t)32 * 1024, Vt[nxt] + (t + 256) * 8);
        }

        // K A-frags (lane = key-within-subtile), shared by both q-groups
        bf16x8 kb[4][2];
        #pragma unroll
        for (int sub = 0; sub < 4; ++sub) {
            const int rowk = sub * 16 + l16;
            kb[sub][0] = *(const bf16x8*)(Kt[cur] + rowk * 64 + ((quad ^ (rowk & 7)) << 3));
            kb[sub][1] = *(const bf16x8*)(Kt[cur] + rowk * 64 + (((quad + 4) ^ (rowk & 7)) << 3));
        }
        // S^T = K Q^T: C col = q (l16), row = key-within-sub (quad*4+r)
        floatx4 sf[2][4];
        #pragma unroll
        for (int g = 0; g < 2; ++g)
            #pragma unroll
            for (int sub = 0; sub < 4; ++sub) {
                floatx4 s = {0.f, 0.f, 0.f, 0.f};
                s = __builtin_amdgcn_mfma_f32_16x16x32_bf16(kb[sub][0], qf[g][0], s, 0, 0, 0);
                s = __builtin_amdgcn_mfma_f32_16x16x32_bf16(kb[sub][1], qf[g][1], s, 0, 0, 0);
                sf[g][sub] = s;
            }
        // exp + mask (int4 per sub: keys kt*64+sub*16+quad*4+r) + row sums
        #pragma unroll
        for (int sub = 0; sub < 4; ++sub) {
            const int4 m4 = *(const int4*)&mrow[kt * 64 + sub * 16 + quad * 4];
            const float md0 = m4.x ? 0.f : -3.0e38f;
            const float md1 = m4.y ? 0.f : -3.0e38f;
            const float md2 = m4.z ? 0.f : -3.0e38f;
            const float md3 = m4.w ? 0.f : -3.0e38f;
            #pragma unroll
            for (int g = 0; g < 2; ++g) {
                float p0 = __expf(sf[g][sub][0] * scale + md0);
                float p1v = __expf(sf[g][sub][1] * scale + md1);
                float p2 = __expf(sf[g][sub][2] * scale + md2);
                float p3 = __expf(sf[g][sub][3] * scale + md3);
                sf[g][sub][0] = p0; sf[g][sub][1] = p1v;
                sf[g][sub][2] = p2; sf[g][sub][3] = p3;
                lsum[g] += p0 + p1v + p2 + p3;
            }
        }
        // P -> Pl[q][key]: packed b64 writes, XOR part-swizzle
        #pragma unroll
        for (int g = 0; g < 2; ++g)
            #pragma unroll
            for (int sub = 0; sub < 4; ++sub) {
                bf16x4 pk = {(bf16)sf[g][sub][0], (bf16)sf[g][sub][1],
                             (bf16)sf[g][sub][2], (bf16)sf[g][sub][3]};
                const int slot = (sub * 2 + (quad >> 1)) ^ (l16 & 7);
                *(bf16x4*)&Pl[wave][(g * 16 + l16) * 64 + slot * 8 + (quad & 1) * 4] = pk;
            }
        bf16x8 af[2][2];
        #pragma unroll
        for (int g = 0; g < 2; ++g)
            #pragma unroll
            for (int hh = 0; hh < 2; ++hh) {
                const int slot = (hh * 4 + quad) ^ (l16 & 7);
                af[g][hh] = *(const bf16x8*)&Pl[wave][(g * 16 + l16) * 64 + slot * 8];
            }
        // O += P V (A = P rows, B = V^T rows), V frags shared by both groups
        #pragma unroll
        for (int dsub = 0; dsub < 4; ++dsub) {
            const int rowd = dsub * 16 + l16;
            bf16x8 v0 = *(const bf16x8*)(Vt[cur] + rowd * 64 + ((quad ^ (rowd & 7)) << 3));
            bf16x8 v1 = *(const bf16x8*)(Vt[cur] + rowd * 64 + (((quad + 4) ^ (rowd & 7)) << 3));
            #pragma unroll
            for (int g = 0; g < 2; ++g) {
                o[g][dsub] = __builtin_amdgcn_mfma_f32_16x16x32_bf16(af[g][0], v0, o[g][dsub], 0, 0, 0);
                o[g][dsub] = __builtin_amdgcn_mfma_f32_16x16x32_bf16(af[g][1], v1, o[g][dsub], 0, 0, 0);
            }
        }
    }

    // reduce row sums (lane l16 = q) across quad groups; broadcast; store
    for (int g = 0; g < 2; ++g) {
        float lr = lsum[g];
        lr += __shfl_xor(lr, 16, 64);
        lr += __shfl_xor(lr, 32, 64);
        const float inv = 1.f / lr;
        float linv[4];
        for (int r = 0; r < 4; ++r) linv[r] = __shfl(inv, quad * 4 + r, 64);
        for (int dsub = 0; dsub < 4; ++dsub) {
            for (int r = 0; r < 4; ++r) {
                const int q = qblk * 128 + wave * 32 + g * 16 + quad * 4 + r;
                const int col = hd * 64 + dsub * 16 + l16;
                Oa[((size_t)(b * NQ + q)) * DIM + col] = (bf16)(o[g][dsub][r] * linv[r]);
            }
        }
    }
}

// ---------------------------------------------------------------------------
// ffn_gemm: proj-style 128x128 tile, BK=64, XOR-swizzled staging, m-minor
// mapping. Yf = Oa + relu(Oa @ Wo^T + bo), fp32. 256 blocks (64m x 4n).
// (The fused ffn_ln re-read all of Wo per 16-row block: 256MB L2 traffic.
//  This splits it back: W traffic 64MB total, LN reads fp32 Yf separately.)
// ---------------------------------------------------------------------------
__global__ __launch_bounds__(256) void ffn_gemm(
    const bf16* __restrict__ Oa, const bf16* __restrict__ W,
    const float* __restrict__ bias, float* __restrict__ Yf)
{
    __shared__ __attribute__((aligned(16))) bf16 As[128 * 64];
    __shared__ __attribute__((aligned(16))) bf16 Bs[128 * 64];
    const int t = threadIdx.x;
    const int wave = t >> 6, lane = t & 63, quad = lane >> 4, l16 = lane & 15;
    const int wr = wave >> 1, wc = wave & 1;
    const int m0 = (blockIdx.x & 63) * 128, n0 = (blockIdx.x >> 6) * 128;

    const int r1 = t >> 3, s1 = t & 7;
    const int p1 = s1 ^ (r1 & 7);
    const bf16* aSrc = Oa + (size_t)(m0 + r1) * DIM + p1 * 8;
    const bf16* wSrc = W  + (size_t)(n0 + r1) * DIM + p1 * 8;

    floatx4 acc[4][4];
    for (int i = 0; i < 4; ++i)
        for (int j = 0; j < 4; ++j) acc[i][j] = (floatx4){0.f, 0.f, 0.f, 0.f};

    for (int kt = 0; kt < 8; ++kt) {
        __syncthreads();
        const int ko = kt * 64;
        #pragma unroll
        for (int j = 0; j < 4; ++j) {
            async16(aSrc + ko + (size_t)j * 32 * DIM, As + (t + j * 256) * 8);
            async16(wSrc + ko + (size_t)j * 32 * DIM, Bs + (t + j * 256) * 8);
        }
        __syncthreads();
        #pragma unroll
        for (int ks = 0; ks < 2; ++ks) {
            bf16x8 af[4], bfr[4];
            #pragma unroll
            for (int mi = 0; mi < 4; ++mi) {
                const int row = wr * 64 + mi * 16 + l16;
                af[mi] = *(const bf16x8*)(As + row * 64 + (((ks * 4 + quad) ^ (row & 7)) << 3));
            }
            #pragma unroll
            for (int ni = 0; ni < 4; ++ni) {
                const int row = wc * 64 + ni * 16 + l16;
                bfr[ni] = *(const bf16x8*)(Bs + row * 64 + (((ks * 4 + quad) ^ (row & 7)) << 3));
            }
            #pragma unroll
            for (int mi = 0; mi < 4; ++mi)
                #pragma unroll
                for (int ni = 0; ni < 4; ++ni)
                    acc[mi][ni] = __builtin_amdgcn_mfma_f32_16x16x32_bf16(
                        af[mi], bfr[ni], acc[mi][ni], 0, 0, 0);
        }
    }

    for (int ni = 0; ni < 4; ++ni) {
        const int n = n0 + wc * 64 + ni * 16 + l16;
        const float bb = bias[n];
        for (int mi = 0; mi < 4; ++mi) {
            for (int r = 0; r < 4; ++r) {
                const int m = m0 + wr * 64 + mi * 16 + quad * 4 + r;
                const float ov = (float)Oa[(size_t)m * DIM + n];
                Yf[(size_t)m * DIM + n] = ov + fmaxf(acc[mi][ni][r] + bb, 0.f);
            }
        }
    }
}

// ---------------------------------------------------------------------------
// ln: LayerNorm over last dim (512). One wave per row, fp32 in/out.
// ---------------------------------------------------------------------------
__global__ __launch_bounds__(256) void ln_kernel(
    const float* __restrict__ Y, const float* __restrict__ gamma,
    const float* __restrict__ beta, float* __restrict__ out)
{
    const int row  = blockIdx.x * 4 + (threadIdx.x >> 6);
    const int lane = threadIdx.x & 63;
    const float* y = Y + (size_t)row * DIM;
    float4 a = ((const float4*)y)[lane];
    float4 c = ((const float4*)y)[lane + 64];
    float s  = a.x + a.y + a.z + a.w + c.x + c.y + c.z + c.w;
    float sq = a.x*a.x + a.y*a.y + a.z*a.z + a.w*a.w
             + c.x*c.x + c.y*c.y + c.z*c.z + c.w*c.w;
    for (int mk = 32; mk >= 1; mk >>= 1) {
        s  += __shfl_xor(s,  mk, 64);
        sq += __shfl_xor(sq, mk, 64);
    }
    const float mu  = s * (1.f / 512.f);
    const float var = sq * (1.f / 512.f) - mu * mu;
    const float inv = rsqrtf(var + 1e-5f);
    float4 g1 = ((const float4*)gamma)[lane];
    float4 g2 = ((const float4*)gamma)[lane + 64];
    float4 b1 = ((const float4*)beta)[lane];
    float4 b2 = ((const float4*)beta)[lane + 64];
    float4 o1, o2;
    o1.x = (a.x - mu) * inv * g1.x + b1.x;
    o1.y = (a.y - mu) * inv * g1.y + b1.y;
    o1.z = (a.z - mu) * inv * g1.z + b1.z;
    o1.w = (a.w - mu) * inv * g1.w + b1.w;
    o2.x = (c.x - mu) * inv * g2.x + b2.x;
    o2.y = (c.y - mu) * inv * g2.y + b2.y;
    o2.z = (c.z - mu) * inv * g2.z + b2.z;
    o2.w = (c.w - mu) * inv * g2.w + b2.w;
    float* orow = out + (size_t)row * DIM;
    ((float4*)orow)[lane]      = o1;
    ((float4*)orow)[lane + 64] = o2;
}

// ---------------------------------------------------------------------------
extern "C" void kernel_launch(void* const* d_in, const int* in_sizes, int n_in,
                              void* d_out, int out_size, void* d_ws, size_t ws_size,
                              hipStream_t stream) {
    const float* Q  = (const float*)d_in[0];
    const float* K  = (const float*)d_in[1];
    const int*   mask = (const int*)d_in[2];
    const float* Wq = (const float*)d_in[3];
    const float* bq = (const float*)d_in[4];
    const float* Wk = (const float*)d_in[5];
    const float* bk = (const float*)d_in[6];
    const float* Wv = (const float*)d_in[7];
    const float* bv = (const float*)d_in[8];
    const float* Wo = (const float*)d_in[9];
    const float* bo = (const float*)d_in[10];
    const float* gamma = (const float*)d_in[11];
    const float* beta  = (const float*)d_in[12];

    char* ws = (char*)d_ws;
    bf16* Wt  = (bf16*)(ws);                   // 2 MB (4 x 512x512 bf16, transposed)
    bf16* Qb  = (bf16*)(ws + 2097152);         // 8 MB
    bf16* Kb  = (bf16*)(ws + 10485760);        // 8 MB
    bf16* Qp  = (bf16*)(ws + 18874368);        // 8 MB  [b,h,q,64]
    bf16* Kp  = (bf16*)(ws + 27262976);        // 8 MB  [b,h,k,64]
    bf16* Vpt = (bf16*)(ws + 35651584);        // 8 MB  [b,h,d,1024]
    bf16* Oa  = (bf16*)(ws + 44040192);        // 8 MB  [b,q,512]
    float* Yf = (float*)(ws + 52428800);       // 16 MB
    float* out = (float*)d_out;

    prep_fused<<<4352, 256, 0, stream>>>(Q, K, Wq, Wk, Wv, Wo, Qb, Kb, Wt);
    proj_fused<<<768, 256, 0, stream>>>(Qb, Kb, Wt, bq, bk, bv, Qp, Kp, Vpt);
    attn_kernel<<<512, 256, 0, stream>>>(Qp, Kp, Vpt, mask, Oa);
    ffn_gemm<<<256, 256, 0, stream>>>(Oa, Wt + 3 * 262144, bo, Yf);
    ln_kernel<<<2048, 256, 0, stream>>>(Yf, gamma, beta, out);
}

// Round 11
// 173.871 us; speedup vs baseline: 1.1332x; 1.0249x over previous
//
#include <hip/hip_runtime.h>

typedef __bf16 bf16;
typedef bf16 bf16x4 __attribute__((ext_vector_type(4)));
typedef bf16 bf16x8 __attribute__((ext_vector_type(8)));
typedef float floatx4 __attribute__((ext_vector_type(4)));

#define NB 8
#define NQ 1024
#define NK 1024
#define DIM 512
#define NH 8
#define DH 64

// async global->LDS, 16B per lane. LDS dest must be wave-uniform base + lane*16B.
__device__ __forceinline__ void async16(const void* g, void* l) {
    __builtin_amdgcn_global_load_lds(
        (const __attribute__((address_space(1))) unsigned int*)(unsigned long long)(g),
        (__attribute__((address_space(3))) unsigned int*)(unsigned long long)(l),
        16, 0, 0);
}

// ---------------------------------------------------------------------------
// prep_fused: blocks [0,4096): cast Q,K fp32->bf16 (float4 vectorized);
//             blocks [4096,4352): Wt[w][n][k] = (bf16)W[k][n], LDS 64x64 tiles.
// ---------------------------------------------------------------------------
__global__ __launch_bounds__(256) void prep_fused(
    const float* __restrict__ Q, const float* __restrict__ K,
    const float* __restrict__ Wq, const float* __restrict__ Wk,
    const float* __restrict__ Wv, const float* __restrict__ Wo,
    bf16* __restrict__ Qb, bf16* __restrict__ Kb, bf16* __restrict__ Wt)
{
    __shared__ bf16 Tl[64][68];
    const int bid = blockIdx.x;
    if (bid < 4096) {
        const int i = bid * 256 + threadIdx.x;   // float4 index
        float4 a = ((const float4*)Q)[i];
        float4 c = ((const float4*)K)[i];
        bf16x4 qa = {(bf16)a.x, (bf16)a.y, (bf16)a.z, (bf16)a.w};
        bf16x4 ka = {(bf16)c.x, (bf16)c.y, (bf16)c.z, (bf16)c.w};
        *(bf16x4*)(Qb + (size_t)i * 4) = qa;
        *(bf16x4*)(Kb + (size_t)i * 4) = ka;
    } else {
        const int bid2 = bid - 4096;
        const int w = bid2 >> 6;
        const int bx = bid2 & 7, by = (bid2 >> 3) & 7;
        const float* W = (w == 0) ? Wq : (w == 1) ? Wk : (w == 2) ? Wv : Wo;
        bf16* out = Wt + (size_t)w * DIM * DIM;
        const int k0 = bx * 64, n0 = by * 64;
        const int tx = threadIdx.x & 15, ty = threadIdx.x >> 4;
        for (int pass = 0; pass < 4; ++pass) {
            int k = ty + pass * 16;
            float4 v = *(const float4*)&W[(size_t)(k0 + k) * DIM + n0 + tx * 4];
            Tl[tx * 4 + 0][k] = (bf16)v.x;
            Tl[tx * 4 + 1][k] = (bf16)v.y;
            Tl[tx * 4 + 2][k] = (bf16)v.z;
            Tl[tx * 4 + 3][k] = (bf16)v.w;
        }
        __syncthreads();
        for (int pass = 0; pass < 4; ++pass) {
            int n = ty + pass * 16;
            bf16x4 ov = *(const bf16x4*)&Tl[n][tx * 4];
            *(bf16x4*)&out[(size_t)(n0 + n) * DIM + k0 + tx * 4] = ov;
        }
    }
}

// ---------------------------------------------------------------------------
// proj_fused: 128x128 tiles, BK=64, XOR-swizzled async staging, m-minor
// block mapping (XCD L2 locality). K-loop LDS double-buffer (attn-style).
// NOTE: LDS buffer selection must be a computed pointer (sh + cur*off) —
// a local array of LDS pointers fails gfx950 codegen (addrspacecast init).
// blocks [0,256):   Q proj -> Qp head layout [b,h,q,64]
// blocks [256,768): KV proj: n<512 -> Kp head layout; n>=512 -> Vpt
//                   [b,h,d,1024] via in-LDS transpose (coalesced stores).
// ---------------------------------------------------------------------------
__global__ __launch_bounds__(256) void proj_fused(
    const bf16* __restrict__ Qb, const bf16* __restrict__ Kb,
    const bf16* __restrict__ Wt,
    const float* __restrict__ bq, const float* __restrict__ bk,
    const float* __restrict__ bv,
    bf16* __restrict__ Qp, bf16* __restrict__ Kp, bf16* __restrict__ Vpt)
{
    __shared__ __attribute__((aligned(16))) bf16 sh[32768];  // 64 KB: A0|A1|B0|B1
    const int t = threadIdx.x;
    const int wave = t >> 6, lane = t & 63, quad = lane >> 4, l16 = lane & 15;
    const int wr = wave >> 1, wc = wave & 1;
    const int bid = blockIdx.x;
    const bool isQ = bid < 256;
    const bf16* A; const bf16* W; int m0, n0;
    if (isQ) { A = Qb; W = Wt;             m0 = (bid & 63) * 128;  n0 = (bid >> 6) * 128; }
    else     { int b2 = bid - 256;
               A = Kb; W = Wt + 512 * DIM; m0 = (b2 & 63) * 128;   n0 = (b2 >> 6) * 128; }

    const int r1 = t >> 3, s1 = t & 7;
    const int p1 = s1 ^ (r1 & 7);          // rows r1+32j keep row&7
    const bf16* aSrc = A + (size_t)(m0 + r1) * DIM + p1 * 8;
    const bf16* wSrc = W + (size_t)(n0 + r1) * DIM + p1 * 8;

    floatx4 acc[4][4];
    for (int i = 0; i < 4; ++i)
        for (int j = 0; j < 4; ++j) acc[i][j] = (floatx4){0.f, 0.f, 0.f, 0.f};

    // prologue: issue kt=0 into buf 0 (A at sh+0, B at sh+16384)
    #pragma unroll
    for (int j = 0; j < 4; ++j) {
        async16(aSrc + (size_t)j * 32 * DIM, sh + (t + j * 256) * 8);
        async16(wSrc + (size_t)j * 32 * DIM, sh + 16384 + (t + j * 256) * 8);
    }

    for (int kt = 0; kt < 8; ++kt) {
        __syncthreads();   // tile kt loads done; all waves done with other buf
        const int cur = kt & 1;
        bf16* Acur = sh + cur * 8192;
        bf16* Bcur = sh + 16384 + cur * 8192;
        if (kt < 7) {
            bf16* Anxt = sh + (1 - cur) * 8192;
            bf16* Bnxt = sh + 16384 + (1 - cur) * 8192;
            const int ko = (kt + 1) * 64;
            #pragma unroll
            for (int j = 0; j < 4; ++j) {
                async16(aSrc + ko + (size_t)j * 32 * DIM, Anxt + (t + j * 256) * 8);
                async16(wSrc + ko + (size_t)j * 32 * DIM, Bnxt + (t + j * 256) * 8);
            }
        }
        #pragma unroll
        for (int ks = 0; ks < 2; ++ks) {
            bf16x8 af[4], bfr[4];
            #pragma unroll
            for (int mi = 0; mi < 4; ++mi) {
                const int row = wr * 64 + mi * 16 + l16;
                af[mi] = *(const bf16x8*)(Acur + row * 64 + (((ks * 4 + quad) ^ (row & 7)) << 3));
            }
            #pragma unroll
            for (int ni = 0; ni < 4; ++ni) {
                const int row = wc * 64 + ni * 16 + l16;
                bfr[ni] = *(const bf16x8*)(Bcur + row * 64 + (((ks * 4 + quad) ^ (row & 7)) << 3));
            }
            #pragma unroll
            for (int mi = 0; mi < 4; ++mi)
                #pragma unroll
                for (int ni = 0; ni < 4; ++ni)
                    acc[mi][ni] = __builtin_amdgcn_mfma_f32_16x16x32_bf16(
                        af[mi], bfr[ni], acc[mi][ni], 0, 0, 0);
        }
    }

    const bool isV = (!isQ) && (n0 >= 512);
    if (!isV) {
        bf16* out = isQ ? Qp : Kp;
        const float* bias = isQ ? bq : bk;
        for (int ni = 0; ni < 4; ++ni) {
            const int n = n0 + wc * 64 + ni * 16 + l16;
            const float bb = bias[n];
            const int hd = n >> 6, d = n & 63;
            for (int mi = 0; mi < 4; ++mi) {
                for (int r = 0; r < 4; ++r) {
                    const int m = m0 + wr * 64 + mi * 16 + quad * 4 + r;
                    const int b = m >> 10, q = m & 1023;
                    out[((size_t)(b * 8 + hd) * 1024 + q) * 64 + d] = (bf16)(acc[mi][ni][r] + bb);
                }
            }
        }
    } else {
        // dump tile (+bias) to LDS as Tb[n][m] (first 32 KB of sh) with
        // chunk-XOR swizzle, then store coalesced rows of Vpt [b,h,d,1024]
        __syncthreads();
        for (int ni = 0; ni < 4; ++ni) {
            const int n = wc * 64 + ni * 16 + l16;           // local n
            const float bb = bv[n0 + n - 512];
            for (int mi = 0; mi < 4; ++mi) {
                const int mb = wr * 64 + mi * 16 + quad * 4;  // local m base (r=0..3)
                const int slot = ((mb >> 3) ^ (n & 15));
                bf16x4 pk = {(bf16)(acc[mi][ni][0] + bb), (bf16)(acc[mi][ni][1] + bb),
                             (bf16)(acc[mi][ni][2] + bb), (bf16)(acc[mi][ni][3] + bb)};
                *(bf16x4*)(sh + n * 128 + slot * 8 + (mb & 7)) = pk;
            }
        }
        __syncthreads();
        const int n = t >> 1, hf = t & 1;
        const int nv = n0 + n - 512, hd = nv >> 6, d = nv & 63;
        const int b = m0 >> 10, qb = m0 & 1023;
        bf16* dst = Vpt + ((size_t)(b * 8 + hd) * 64 + d) * 1024 + qb + hf * 64;
        #pragma unroll
        for (int j = 0; j < 8; ++j) {
            const int ch = hf * 8 + j;
            const int slot = ch ^ (n & 15);
            bf16x8 v8 = *(const bf16x8*)(sh + n * 128 + slot * 8);
            *(bf16x8*)(dst + j * 8) = v8;
        }
    }
}

// ---------------------------------------------------------------------------
// attn: flash attention per (b,h). 512 blocks x 4 waves, 128 q/block,
// 32 q/wave (two 16-row groups sharing K/V frags). __expf. S^T trick
// (A=K, B=Q) -> packed b64 P writes. K/V LDS double-buffer.
// ---------------------------------------------------------------------------
__global__ __launch_bounds__(256) void attn_kernel(
    const bf16* __restrict__ Qp, const bf16* __restrict__ Kp,
    const bf16* __restrict__ Vpt, const int* __restrict__ mask,
    bf16* __restrict__ Oa)
{
    const int bh = blockIdx.x & 63, qblk = blockIdx.x >> 6;  // qblk 0..7
    const int b = bh >> 3, hd = bh & 7;
    const int t = threadIdx.x;
    const int wave = t >> 6, lane = t & 63, quad = lane >> 4, l16 = lane & 15;
    const float scale = 1.25f;   // 1/(sqrt(64)*0.1)

    __shared__ __attribute__((aligned(16))) bf16 Kt[2][64 * 64];
    __shared__ __attribute__((aligned(16))) bf16 Vt[2][64 * 64];
    __shared__ __attribute__((aligned(16))) bf16 Pl[4][32 * 64];

    const bf16* Qbase = Qp + ((size_t)bh * NQ + qblk * 128 + wave * 32) * DH;
    const bf16* Kbase = Kp + (size_t)bh * NK * DH;
    const bf16* Vbase = Vpt + (size_t)bh * DH * NK;
    const int* mrow = mask + b * NK;

    bf16x8 qf[2][2];
    for (int g = 0; g < 2; ++g)
        for (int hh = 0; hh < 2; ++hh)
            qf[g][hh] = *(const bf16x8*)(Qbase + (g * 16 + l16) * DH + hh * 32 + quad * 8);

    floatx4 o[2][4];
    float lsum[2];
    for (int g = 0; g < 2; ++g) {
        lsum[g] = 0.f;
        for (int i = 0; i < 4; ++i) o[g][i] = (floatx4){0.f, 0.f, 0.f, 0.f};
    }

    const int r1 = t >> 3, s1 = t & 7;
    const int p1 = s1 ^ (r1 & 7);          // (r1+32)&7 == r1&7
    const bf16* kSrc = Kbase + r1 * 64 + p1 * 8;            // + kt*4096
    const bf16* vSrc = Vbase + (size_t)r1 * 1024 + p1 * 8;  // + kt*64

    // prologue: issue tile 0 into buf 0
    async16(kSrc, Kt[0] + t * 8);
    async16(kSrc + 32 * 64, Kt[0] + (t + 256) * 8);
    async16(vSrc, Vt[0] + t * 8);
    async16(vSrc + (size_t)32 * 1024, Vt[0] + (t + 256) * 8);

    for (int kt = 0; kt < NK / 64; ++kt) {
        __syncthreads();   // tile kt loads complete; all waves done with other buf
        const int cur = kt & 1;
        if (kt < NK / 64 - 1) {
            const int nxt = 1 - cur;
            async16(kSrc + (kt + 1) * 4096, Kt[nxt] + t * 8);
            async16(kSrc + (kt + 1) * 4096 + 32 * 64, Kt[nxt] + (t + 256) * 8);
            async16(vSrc + (kt + 1) * 64, Vt[nxt] + t * 8);
            async16(vSrc + (kt + 1) * 64 + (size_t)32 * 1024, Vt[nxt] + (t + 256) * 8);
        }

        // K A-frags (lane = key-within-subtile), shared by both q-groups
        bf16x8 kb[4][2];
        #pragma unroll
        for (int sub = 0; sub < 4; ++sub) {
            const int rowk = sub * 16 + l16;
            kb[sub][0] = *(const bf16x8*)(Kt[cur] + rowk * 64 + ((quad ^ (rowk & 7)) << 3));
            kb[sub][1] = *(const bf16x8*)(Kt[cur] + rowk * 64 + (((quad + 4) ^ (rowk & 7)) << 3));
        }
        // S^T = K Q^T: C col = q (l16), row = key-within-sub (quad*4+r)
        floatx4 sf[2][4];
        #pragma unroll
        for (int g = 0; g < 2; ++g)
            #pragma unroll
            for (int sub = 0; sub < 4; ++sub) {
                floatx4 s = {0.f, 0.f, 0.f, 0.f};
                s = __builtin_amdgcn_mfma_f32_16x16x32_bf16(kb[sub][0], qf[g][0], s, 0, 0, 0);
                s = __builtin_amdgcn_mfma_f32_16x16x32_bf16(kb[sub][1], qf[g][1], s, 0, 0, 0);
                sf[g][sub] = s;
            }
        // exp + mask (int4 per sub: keys kt*64+sub*16+quad*4+r) + row sums
        #pragma unroll
        for (int sub = 0; sub < 4; ++sub) {
            const int4 m4 = *(const int4*)&mrow[kt * 64 + sub * 16 + quad * 4];
            const float md0 = m4.x ? 0.f : -3.0e38f;
            const float md1 = m4.y ? 0.f : -3.0e38f;
            const float md2 = m4.z ? 0.f : -3.0e38f;
            const float md3 = m4.w ? 0.f : -3.0e38f;
            #pragma unroll
            for (int g = 0; g < 2; ++g) {
                float p0 = __expf(sf[g][sub][0] * scale + md0);
                float p1v = __expf(sf[g][sub][1] * scale + md1);
                float p2 = __expf(sf[g][sub][2] * scale + md2);
                float p3 = __expf(sf[g][sub][3] * scale + md3);
                sf[g][sub][0] = p0; sf[g][sub][1] = p1v;
                sf[g][sub][2] = p2; sf[g][sub][3] = p3;
                lsum[g] += p0 + p1v + p2 + p3;
            }
        }
        // P -> Pl[q][key]: packed b64 writes, XOR part-swizzle
        #pragma unroll
        for (int g = 0; g < 2; ++g)
            #pragma unroll
            for (int sub = 0; sub < 4; ++sub) {
                bf16x4 pk = {(bf16)sf[g][sub][0], (bf16)sf[g][sub][1],
                             (bf16)sf[g][sub][2], (bf16)sf[g][sub][3]};
                const int slot = (sub * 2 + (quad >> 1)) ^ (l16 & 7);
                *(bf16x4*)&Pl[wave][(g * 16 + l16) * 64 + slot * 8 + (quad & 1) * 4] = pk;
            }
        bf16x8 af[2][2];
        #pragma unroll
        for (int g = 0; g < 2; ++g)
            #pragma unroll
            for (int hh = 0; hh < 2; ++hh) {
                const int slot = (hh * 4 + quad) ^ (l16 & 7);
                af[g][hh] = *(const bf16x8*)&Pl[wave][(g * 16 + l16) * 64 + slot * 8];
            }
        // O += P V (A = P rows, B = V^T rows), V frags shared by both groups
        #pragma unroll
        for (int dsub = 0; dsub < 4; ++dsub) {
            const int rowd = dsub * 16 + l16;
            bf16x8 v0 = *(const bf16x8*)(Vt[cur] + rowd * 64 + ((quad ^ (rowd & 7)) << 3));
            bf16x8 v1 = *(const bf16x8*)(Vt[cur] + rowd * 64 + (((quad + 4) ^ (rowd & 7)) << 3));
            #pragma unroll
            for (int g = 0; g < 2; ++g) {
                o[g][dsub] = __builtin_amdgcn_mfma_f32_16x16x32_bf16(af[g][0], v0, o[g][dsub], 0, 0, 0);
                o[g][dsub] = __builtin_amdgcn_mfma_f32_16x16x32_bf16(af[g][1], v1, o[g][dsub], 0, 0, 0);
            }
        }
    }

    // reduce row sums (lane l16 = q) across quad groups; broadcast; store
    for (int g = 0; g < 2; ++g) {
        float lr = lsum[g];
        lr += __shfl_xor(lr, 16, 64);
        lr += __shfl_xor(lr, 32, 64);
        const float inv = 1.f / lr;
        float linv[4];
        for (int r = 0; r < 4; ++r) linv[r] = __shfl(inv, quad * 4 + r, 64);
        for (int dsub = 0; dsub < 4; ++dsub) {
            for (int r = 0; r < 4; ++r) {
                const int q = qblk * 128 + wave * 32 + g * 16 + quad * 4 + r;
                const int col = hd * 64 + dsub * 16 + l16;
                Oa[((size_t)(b * NQ + q)) * DIM + col] = (bf16)(o[g][dsub][r] * linv[r]);
            }
        }
    }
}

// ---------------------------------------------------------------------------
// ffn_gemm: 128x128 tile, BK=64, XOR-swizzled staging, m-minor mapping,
// K-loop double-buffer (computed LDS pointers — see proj note).
// Yb (bf16) = Oa + relu(Oa @ Wo^T + bo). 256 blocks.
// ---------------------------------------------------------------------------
__global__ __launch_bounds__(256) void ffn_gemm(
    const bf16* __restrict__ Oa, const bf16* __restrict__ W,
    const float* __restrict__ bias, bf16* __restrict__ Yb)
{
    __shared__ __attribute__((aligned(16))) bf16 sh[32768];  // 64 KB: A0|A1|B0|B1
    const int t = threadIdx.x;
    const int wave = t >> 6, lane = t & 63, quad = lane >> 4, l16 = lane & 15;
    const int wr = wave >> 1, wc = wave & 1;
    const int m0 = (blockIdx.x & 63) * 128, n0 = (blockIdx.x >> 6) * 128;

    const int r1 = t >> 3, s1 = t & 7;
    const int p1 = s1 ^ (r1 & 7);
    const bf16* aSrc = Oa + (size_t)(m0 + r1) * DIM + p1 * 8;
    const bf16* wSrc = W  + (size_t)(n0 + r1) * DIM + p1 * 8;

    floatx4 acc[4][4];
    for (int i = 0; i < 4; ++i)
        for (int j = 0; j < 4; ++j) acc[i][j] = (floatx4){0.f, 0.f, 0.f, 0.f};

    #pragma unroll
    for (int j = 0; j < 4; ++j) {
        async16(aSrc + (size_t)j * 32 * DIM, sh + (t + j * 256) * 8);
        async16(wSrc + (size_t)j * 32 * DIM, sh + 16384 + (t + j * 256) * 8);
    }

    for (int kt = 0; kt < 8; ++kt) {
        __syncthreads();
        const int cur = kt & 1;
        bf16* Acur = sh + cur * 8192;
        bf16* Bcur = sh + 16384 + cur * 8192;
        if (kt < 7) {
            bf16* Anxt = sh + (1 - cur) * 8192;
            bf16* Bnxt = sh + 16384 + (1 - cur) * 8192;
            const int ko = (kt + 1) * 64;
            #pragma unroll
            for (int j = 0; j < 4; ++j) {
                async16(aSrc + ko + (size_t)j * 32 * DIM, Anxt + (t + j * 256) * 8);
                async16(wSrc + ko + (size_t)j * 32 * DIM, Bnxt + (t + j * 256) * 8);
            }
        }
        #pragma unroll
        for (int ks = 0; ks < 2; ++ks) {
            bf16x8 af[4], bfr[4];
            #pragma unroll
            for (int mi = 0; mi < 4; ++mi) {
                const int row = wr * 64 + mi * 16 + l16;
                af[mi] = *(const bf16x8*)(Acur + row * 64 + (((ks * 4 + quad) ^ (row & 7)) << 3));
            }
            #pragma unroll
            for (int ni = 0; ni < 4; ++ni) {
                const int row = wc * 64 + ni * 16 + l16;
                bfr[ni] = *(const bf16x8*)(Bcur + row * 64 + (((ks * 4 + quad) ^ (row & 7)) << 3));
            }
            #pragma unroll
            for (int mi = 0; mi < 4; ++mi)
                #pragma unroll
                for (int ni = 0; ni < 4; ++ni)
                    acc[mi][ni] = __builtin_amdgcn_mfma_f32_16x16x32_bf16(
                        af[mi], bfr[ni], acc[mi][ni], 0, 0, 0);
        }
    }

    for (int ni = 0; ni < 4; ++ni) {
        const int n = n0 + wc * 64 + ni * 16 + l16;
        const float bb = bias[n];
        for (int mi = 0; mi < 4; ++mi) {
            for (int r = 0; r < 4; ++r) {
                const int m = m0 + wr * 64 + mi * 16 + quad * 4 + r;
                const float ov = (float)Oa[(size_t)m * DIM + n];
                Yb[(size_t)m * DIM + n] = (bf16)(ov + fmaxf(acc[mi][ni][r] + bb, 0.f));
            }
        }
    }
}

// ---------------------------------------------------------------------------
// ln: LayerNorm over last dim (512). One wave per row; bf16 in, fp32 out.
// Each lane owns 8 contiguous cols (one bf16x8 load).
// ---------------------------------------------------------------------------
__global__ __launch_bounds__(256) void ln_kernel(
    const bf16* __restrict__ Y, const float* __restrict__ gamma,
    const float* __restrict__ beta, float* __restrict__ out)
{
    const int row  = blockIdx.x * 4 + (threadIdx.x >> 6);
    const int lane = threadIdx.x & 63;
    bf16x8 v = *(const bf16x8*)(Y + (size_t)row * DIM + lane * 8);
    float f[8];
    float s = 0.f, sq = 0.f;
    #pragma unroll
    for (int j = 0; j < 8; ++j) {
        f[j] = (float)v[j];
        s += f[j];
        sq += f[j] * f[j];
    }
    for (int mk = 32; mk >= 1; mk >>= 1) {
        s  += __shfl_xor(s,  mk, 64);
        sq += __shfl_xor(sq, mk, 64);
    }
    const float mu  = s * (1.f / 512.f);
    const float var = sq * (1.f / 512.f) - mu * mu;
    const float inv = rsqrtf(var + 1e-5f);
    float4 g1 = ((const float4*)gamma)[lane * 2];
    float4 g2 = ((const float4*)gamma)[lane * 2 + 1];
    float4 b1 = ((const float4*)beta)[lane * 2];
    float4 b2 = ((const float4*)beta)[lane * 2 + 1];
    float4 o1, o2;
    o1.x = (f[0] - mu) * inv * g1.x + b1.x;
    o1.y = (f[1] - mu) * inv * g1.y + b1.y;
    o1.z = (f[2] - mu) * inv * g1.z + b1.z;
    o1.w = (f[3] - mu) * inv * g1.w + b1.w;
    o2.x = (f[4] - mu) * inv * g2.x + b2.x;
    o2.y = (f[5] - mu) * inv * g2.y + b2.y;
    o2.z = (f[6] - mu) * inv * g2.z + b2.z;
    o2.w = (f[7] - mu) * inv * g2.w + b2.w;
    float* orow = out + (size_t)row * DIM;
    ((float4*)orow)[lane * 2]     = o1;
    ((float4*)orow)[lane * 2 + 1] = o2;
}

// ---------------------------------------------------------------------------
extern "C" void kernel_launch(void* const* d_in, const int* in_sizes, int n_in,
                              void* d_out, int out_size, void* d_ws, size_t ws_size,
                              hipStream_t stream) {
    const float* Q  = (const float*)d_in[0];
    const float* K  = (const float*)d_in[1];
    const int*   mask = (const int*)d_in[2];
    const float* Wq = (const float*)d_in[3];
    const float* bq = (const float*)d_in[4];
    const float* Wk = (const float*)d_in[5];
    const float* bk = (const float*)d_in[6];
    const float* Wv = (const float*)d_in[7];
    const float* bv = (const float*)d_in[8];
    const float* Wo = (const float*)d_in[9];
    const float* bo = (const float*)d_in[10];
    const float* gamma = (const float*)d_in[11];
    const float* beta  = (const float*)d_in[12];

    char* ws = (char*)d_ws;
    bf16* Wt  = (bf16*)(ws);                   // 2 MB (4 x 512x512 bf16, transposed)
    bf16* Qb  = (bf16*)(ws + 2097152);         // 8 MB
    bf16* Kb  = (bf16*)(ws + 10485760);        // 8 MB
    bf16* Qp  = (bf16*)(ws + 18874368);        // 8 MB  [b,h,q,64]
    bf16* Kp  = (bf16*)(ws + 27262976);        // 8 MB  [b,h,k,64]
    bf16* Vpt = (bf16*)(ws + 35651584);        // 8 MB  [b,h,d,1024]
    bf16* Oa  = (bf16*)(ws + 44040192);        // 8 MB  [b,q,512]
    bf16* Yb  = (bf16*)(ws + 52428800);        // 8 MB  [b,q,512] bf16
    float* out = (float*)d_out;

    prep_fused<<<4352, 256, 0, stream>>>(Q, K, Wq, Wk, Wv, Wo, Qb, Kb, Wt);
    proj_fused<<<768, 256, 0, stream>>>(Qb, Kb, Wt, bq, bk, bv, Qp, Kp, Vpt);
    attn_kernel<<<512, 256, 0, stream>>>(Qp, Kp, Vpt, mask, Oa);
    ffn_gemm<<<256, 256, 0, stream>>>(Oa, Wt + 3 * 262144, bo, Yb);
    ln_kernel<<<2048, 256, 0, stream>>>(Yb, gamma, beta, out);
}